// Round 5
// baseline (679.165 us; speedup 1.0000x reference)
//
#include <hip/hip_runtime.h>

#define NN 4096
#define HH 256
#define EE 131072

__device__ __constant__ float LN_EPS = 1e-5f;
#define ATT_SCALE 0.08838834764831845f
#define ATT_SHIFT 30.0f

typedef __attribute__((ext_vector_type(8))) short bf16x8_t;
typedef __attribute__((ext_vector_type(4))) float f32x4_t;

__device__ inline ushort f2b(float f) {
  uint u = __float_as_uint(f);
  uint r = (u + 0x7FFF + ((u >> 16) & 1)) >> 16;
  return (ushort)r;
}
__device__ inline float b2f(ushort u) { return __uint_as_float(((uint)u) << 16); }

// ---------------- CSR build ----------------
__global__ void hist_kernel(const int* __restrict__ ei, int* __restrict__ cnt) {
  int e = blockIdx.x * blockDim.x + threadIdx.x;
  if (e < EE) atomicAdd(&cnt[ei[EE + e]], 1);
}

__global__ __launch_bounds__(1024) void scan_kernel(int* __restrict__ cnt_cursor,
                                                    int* __restrict__ rowptr,
                                                    float* __restrict__ invdeg) {
  __shared__ int part[1024];
  int t = threadIdx.x;
  int base = t * 4;
  int cs[4];
  int s = 0;
  for (int u = 0; u < 4; ++u) { cs[u] = cnt_cursor[base + u]; s += cs[u]; }
  part[t] = s;
  __syncthreads();
  for (int off = 1; off < 1024; off <<= 1) {
    int add = (t >= off) ? part[t - off] : 0;
    int v = part[t];
    __syncthreads();
    part[t] = v + add;
    __syncthreads();
  }
  int excl = (t > 0) ? part[t - 1] : 0;
  for (int u = 0; u < 4; ++u) {
    rowptr[base + u] = excl;
    cnt_cursor[base + u] = excl;
    invdeg[base + u] = 1.0f / (float)max(cs[u], 1);
    excl += cs[u];
  }
  if (t == 1023) rowptr[NN] = excl;
}

__global__ void fill_kernel(const int* __restrict__ ei, int* __restrict__ cursor,
                            int* __restrict__ col) {
  int e = blockIdx.x * blockDim.x + threadIdx.x;
  if (e < EE) {
    int d = ei[EE + e];
    int p = atomicAdd(&cursor[d], 1);
    col[p] = ei[e];
  }
}

// ---------------- casts ----------------
__global__ __launch_bounds__(256) void castw(const float* __restrict__ in,
                                             ushort* __restrict__ out) {
  int i4 = (blockIdx.x * 256 + threadIdx.x) * 4;
  float4 v = *(const float4*)(in + i4);
  ushort4 w;
  w.x = f2b(v.x); w.y = f2b(v.y); w.z = f2b(v.z); w.w = f2b(v.w);
  *(ushort4*)(out + i4) = w;
}

// conv weight repack: out[j][o][ks*256+ii] = w[j][o][ii][ks]
__global__ __launch_bounds__(256) void castconv(const float* __restrict__ w,
                                                ushort* __restrict__ o) {
  int idx = blockIdx.x * 256 + threadIdx.x;
  int j = idx / 196608;
  int rem = idx - j * 196608;
  int oc = rem / 768;
  int kk = rem - oc * 768;
  int ks = kk >> 8, ii = kk & 255;
  o[idx] = f2b(w[j * 196608 + oc * 768 + ii * 3 + ks]);
}

// ---------------- neighbor mean aggregation (bf16 in/out) ----------------
__global__ __launch_bounds__(64) void agg_kernel(const ushort* __restrict__ hb,
                                                 const int* __restrict__ rowptr,
                                                 const int* __restrict__ col,
                                                 const float* __restrict__ invdeg,
                                                 ushort* __restrict__ aggb) {
  int n = blockIdx.x;
  int t = threadIdx.x;
  int s = rowptr[n], e = rowptr[n + 1];
  float a0 = 0.f, a1 = 0.f, a2 = 0.f, a3 = 0.f;
  for (int j = s; j < e; ++j) {
    int c = col[j];
    ushort4 u = *(const ushort4*)(hb + (size_t)c * HH + t * 4);
    a0 += b2f(u.x); a1 += b2f(u.y); a2 += b2f(u.z); a3 += b2f(u.w);
  }
  float id = invdeg[n];
  ushort4 w;
  w.x = f2b(a0 * id); w.y = f2b(a1 * id); w.z = f2b(a2 * id); w.w = f2b(a3 * id);
  *(ushort4*)(aggb + (size_t)n * HH + t * 4) = w;
}

// ---------------- bf16 MFMA GEMM, BM=64 BN=128 BK=32 (in_proj / out_proj) ----------------
__global__ __launch_bounds__(256) void gemm_mfma(
    const ushort* __restrict__ A0, const ushort* __restrict__ A1,
    const ushort* __restrict__ B0,
    const float* __restrict__ bias, float* __restrict__ Cf, ushort* __restrict__ Cb,
    int M, int Nn, int K, int KHA) {
  __shared__ ushort Alds[64][40];
  __shared__ ushort Blds[128][40];
  int t = threadIdx.x;
  int w = t >> 6, l = t & 63, quad = l >> 4, lr = l & 15;
  int wm = w & 1, wn = w >> 1;
  int m0 = blockIdx.x * 64, n0 = blockIdx.y * 128;
  int sr = t >> 2, sc8 = (t & 3) * 8;
  f32x4_t acc[2][4];
#pragma unroll
  for (int s = 0; s < 2; ++s)
#pragma unroll
    for (int q = 0; q < 4; ++q) acc[s][q] = (f32x4_t){0.f, 0.f, 0.f, 0.f};

  for (int k0 = 0; k0 < K; k0 += 32) {
    int kk = k0 + sc8;
    const ushort* ap = (kk < KHA) ? (A0 + (size_t)(m0 + sr) * KHA + kk)
                                  : (A1 + (size_t)(m0 + sr) * (K - KHA) + (kk - KHA));
    uint4 av = *(const uint4*)ap;
    uint4 bv0 = *(const uint4*)(B0 + (size_t)(n0 + sr) * K + kk);
    uint4 bv1 = *(const uint4*)(B0 + (size_t)(n0 + 64 + sr) * K + kk);
    __syncthreads();
    *(uint4*)&Alds[sr][sc8] = av;
    *(uint4*)&Blds[sr][sc8] = bv0;
    *(uint4*)&Blds[64 + sr][sc8] = bv1;
    __syncthreads();
    bf16x8_t af[2], bf[4];
#pragma unroll
    for (int s = 0; s < 2; ++s)
      af[s] = *(const bf16x8_t*)&Alds[wm * 32 + s * 16 + lr][quad * 8];
#pragma unroll
    for (int q = 0; q < 4; ++q)
      bf[q] = *(const bf16x8_t*)&Blds[wn * 64 + q * 16 + lr][quad * 8];
#pragma unroll
    for (int s = 0; s < 2; ++s)
#pragma unroll
      for (int q = 0; q < 4; ++q)
        acc[s][q] = __builtin_amdgcn_mfma_f32_16x16x32_bf16(af[s], bf[q], acc[s][q], 0, 0, 0);
  }
#pragma unroll
  for (int s = 0; s < 2; ++s) {
#pragma unroll
    for (int q = 0; q < 4; ++q) {
      int n = n0 + wn * 64 + q * 16 + lr;
      float bb = bias[n];
#pragma unroll
      for (int r = 0; r < 4; ++r) {
        int m = m0 + wm * 32 + s * 16 + quad * 4 + r;
        float v = acc[s][q][r] + bb;
        if (Cf) Cf[(size_t)m * Nn + n] = v;
        if (Cb) Cb[(size_t)m * Nn + n] = f2b(v);
      }
    }
  }
}

// ---------------- bf16 MFMA GEMM, BM=64 BN=64 BK=32 (SAGE / fuse) ----------------
__global__ __launch_bounds__(256) void gemm_mfma64(
    const ushort* __restrict__ A0, const ushort* __restrict__ A1,
    const ushort* __restrict__ B0, const ushort* __restrict__ B1,
    const float* __restrict__ bias, float* __restrict__ Cf,
    int M, int Nn, int K, int KHA, int KHB) {
  __shared__ ushort Alds[64][40];
  __shared__ ushort Blds[64][40];
  int t = threadIdx.x;
  int w = t >> 6, l = t & 63, quad = l >> 4, lr = l & 15;
  int wm = w & 1, wn = w >> 1;
  int m0 = blockIdx.x * 64, n0 = blockIdx.y * 64;
  int sr = t >> 2, sc8 = (t & 3) * 8;
  f32x4_t acc[2][2];
#pragma unroll
  for (int s = 0; s < 2; ++s)
#pragma unroll
    for (int q = 0; q < 2; ++q) acc[s][q] = (f32x4_t){0.f, 0.f, 0.f, 0.f};

  for (int k0 = 0; k0 < K; k0 += 32) {
    int kk = k0 + sc8;
    const ushort* ap = (kk < KHA) ? (A0 + (size_t)(m0 + sr) * KHA + kk)
                                  : (A1 + (size_t)(m0 + sr) * (K - KHA) + (kk - KHA));
    uint4 av = *(const uint4*)ap;
    const ushort* bp = (kk < KHB) ? (B0 + (size_t)(n0 + sr) * KHB + kk)
                                  : (B1 + (size_t)(n0 + sr) * (K - KHB) + (kk - KHB));
    uint4 bv = *(const uint4*)bp;
    __syncthreads();
    *(uint4*)&Alds[sr][sc8] = av;
    *(uint4*)&Blds[sr][sc8] = bv;
    __syncthreads();
    bf16x8_t af[2], bf[2];
#pragma unroll
    for (int s = 0; s < 2; ++s)
      af[s] = *(const bf16x8_t*)&Alds[wm * 32 + s * 16 + lr][quad * 8];
#pragma unroll
    for (int q = 0; q < 2; ++q)
      bf[q] = *(const bf16x8_t*)&Blds[wn * 32 + q * 16 + lr][quad * 8];
#pragma unroll
    for (int s = 0; s < 2; ++s)
#pragma unroll
      for (int q = 0; q < 2; ++q)
        acc[s][q] = __builtin_amdgcn_mfma_f32_16x16x32_bf16(af[s], bf[q], acc[s][q], 0, 0, 0);
  }
#pragma unroll
  for (int s = 0; s < 2; ++s) {
#pragma unroll
    for (int q = 0; q < 2; ++q) {
      int n = n0 + wn * 32 + q * 16 + lr;
      float bb = bias[n];
#pragma unroll
      for (int r = 0; r < 4; ++r) {
        int m = m0 + wm * 32 + s * 16 + quad * 4 + r;
        Cf[(size_t)m * Nn + n] = acc[s][q][r] + bb;
      }
    }
  }
}

// ---------------- conv1d(k=3,pad=1) as MFMA GEMM BN=64, epilogue relu(x+b), fp32 out ----------------
__global__ __launch_bounds__(256) void gemm_conv_mfma(
    const ushort* __restrict__ Ab, const ushort* __restrict__ B,
    const float* __restrict__ bias, float* __restrict__ Cf) {
  __shared__ ushort Alds[64][40];
  __shared__ ushort Blds[64][40];
  int t = threadIdx.x;
  int w = t >> 6, l = t & 63, quad = l >> 4, lr = l & 15;
  int wm = w & 1, wn = w >> 1;
  int m0 = blockIdx.x * 64, n0 = blockIdx.y * 64;
  int sr = t >> 2, sc8 = (t & 3) * 8;
  f32x4_t acc[2][2];
#pragma unroll
  for (int s = 0; s < 2; ++s)
#pragma unroll
    for (int q = 0; q < 2; ++q) acc[s][q] = (f32x4_t){0.f, 0.f, 0.f, 0.f};

  for (int k0 = 0; k0 < 768; k0 += 32) {
    int kk = k0 + sc8;
    int ks = kk >> 8, ii = kk & 255;
    int nr = m0 + sr + ks - 1;
    uint4 av = make_uint4(0u, 0u, 0u, 0u);
    if (nr >= 0 && nr < NN) av = *(const uint4*)(Ab + (size_t)nr * HH + ii);
    uint4 bv = *(const uint4*)(B + (size_t)(n0 + sr) * 768 + kk);
    __syncthreads();
    *(uint4*)&Alds[sr][sc8] = av;
    *(uint4*)&Blds[sr][sc8] = bv;
    __syncthreads();
    bf16x8_t af[2], bf[2];
#pragma unroll
    for (int s = 0; s < 2; ++s)
      af[s] = *(const bf16x8_t*)&Alds[wm * 32 + s * 16 + lr][quad * 8];
#pragma unroll
    for (int q = 0; q < 2; ++q)
      bf[q] = *(const bf16x8_t*)&Blds[wn * 32 + q * 16 + lr][quad * 8];
#pragma unroll
    for (int s = 0; s < 2; ++s)
#pragma unroll
      for (int q = 0; q < 2; ++q)
        acc[s][q] = __builtin_amdgcn_mfma_f32_16x16x32_bf16(af[s], bf[q], acc[s][q], 0, 0, 0);
  }
#pragma unroll
  for (int s = 0; s < 2; ++s) {
#pragma unroll
    for (int q = 0; q < 2; ++q) {
      int n = n0 + wn * 32 + q * 16 + lr;
      float bb = bias[n];
#pragma unroll
      for (int r = 0; r < 4; ++r) {
        int m = m0 + wm * 32 + s * 16 + quad * 4 + r;
        Cf[(size_t)m * HH + n] = fmaxf(acc[s][q][r] + bb, 0.f);
      }
    }
  }
}

// ---------------- LayerNorm, wave-per-row, no LDS/barriers ----------------
__global__ __launch_bounds__(256) void ln_fuse(
    const float* __restrict__ x, const float* __restrict__ g, const float* __restrict__ b,
    const float* __restrict__ res, float* __restrict__ outf, ushort* __restrict__ outb,
    int D, int do_ln, int relu_res) {
  int w = threadIdx.x >> 6, l = threadIdx.x & 63;
  int row = blockIdx.x * 4 + w;
  const float* xr = x + (size_t)row * D;
  int nv = D >> 8;
  float4 v[2];
  float s = 0.f, sq = 0.f;
  for (int u = 0; u < nv; ++u) {
    v[u] = *(const float4*)(xr + l * 4 + (u << 8));
    s += v[u].x + v[u].y + v[u].z + v[u].w;
    sq += v[u].x * v[u].x + v[u].y * v[u].y + v[u].z * v[u].z + v[u].w * v[u].w;
  }
  float m = 0.f, inv = 1.f;
  if (do_ln) {
    for (int off = 1; off < 64; off <<= 1) {
      s += __shfl_xor(s, off);
      sq += __shfl_xor(sq, off);
    }
    m = s / D;
    inv = rsqrtf(sq / D - m * m + LN_EPS);
  }
  for (int u = 0; u < nv; ++u) {
    int c = l * 4 + (u << 8);
    float4 y = v[u];
    if (do_ln) {
      float4 gg = *(const float4*)(g + c);
      float4 bb = *(const float4*)(b + c);
      y.x = (y.x - m) * inv * gg.x + bb.x;
      y.y = (y.y - m) * inv * gg.y + bb.y;
      y.z = (y.z - m) * inv * gg.z + bb.z;
      y.w = (y.w - m) * inv * gg.w + bb.w;
    }
    if (relu_res) {
      float4 rr = *(const float4*)(res + (size_t)row * D + c);
      y.x = fmaxf(y.x, 0.f) + rr.x;
      y.y = fmaxf(y.y, 0.f) + rr.y;
      y.z = fmaxf(y.z, 0.f) + rr.z;
      y.w = fmaxf(y.w, 0.f) + rr.w;
    }
    if (outf) *(float4*)(outf + (size_t)row * D + c) = y;
    if (outb) {
      ushort4 yb;
      yb.x = f2b(y.x); yb.y = f2b(y.y); yb.z = f2b(y.z); yb.w = f2b(y.w);
      *(ushort4*)(outb + (size_t)row * D + c) = yb;
    }
  }
}

// ---------------- V transpose: qkvb[n][1024+dg] -> Vt[dg][n] (bf16) ----------------
__global__ __launch_bounds__(256) void vtrans(const ushort* __restrict__ qkvb,
                                              ushort* __restrict__ Vt) {
  __shared__ ushort tile[32][34];
  int t = threadIdx.x;
  int n0 = blockIdx.x * 32, d0 = blockIdx.y * 32;
  int tx = t & 31, ty = t >> 5;
#pragma unroll
  for (int u = 0; u < 4; ++u) {
    int r = ty + 8 * u;
    tile[r][tx] = qkvb[(size_t)(n0 + r) * 1536 + 1024 + d0 + tx];
  }
  __syncthreads();
#pragma unroll
  for (int u = 0; u < 4; ++u) {
    int dy = ty + 8 * u;
    Vt[(size_t)(d0 + dy) * NN + n0 + tx] = tile[tx][dy];
  }
}

// ---------------- bf16 MFMA flash attention, BQ=64 (4 waves), split-KV S=2 ----------------
// Writes fp32 partial numerators + denominators; combine kernel finishes.
__global__ __launch_bounds__(256) void attn_mfma(const ushort* __restrict__ qkvb,
                                                 const ushort* __restrict__ Vt,
                                                 float* __restrict__ Onum,
                                                 float* __restrict__ dpart) {
  __shared__ ushort Klds[64][136];
  __shared__ ushort Vlds[128][72];
  __shared__ ushort Plds[4][16][72];

  int t = threadIdx.x;
  int w = t >> 6, l = t & 63;
  int quad = l >> 4, lr = l & 15;
  int head = blockIdx.y;
  int q0 = blockIdx.x * 64;
  int kvs = blockIdx.z;

  bf16x8_t qf[4];
#pragma unroll
  for (int ks = 0; ks < 4; ++ks)
    qf[ks] = *(const bf16x8_t*)(qkvb + (size_t)(q0 + w * 16 + lr) * 1536 + head * 128 +
                                ks * 32 + quad * 8);

  f32x4_t of[8];
#pragma unroll
  for (int dt = 0; dt < 8; ++dt) of[dt] = (f32x4_t){0.f, 0.f, 0.f, 0.f};
  float den[4] = {0.f, 0.f, 0.f, 0.f};

  for (int kt = 0; kt < 32; ++kt) {
    int k0 = kvs * 2048 + kt * 64;
    __syncthreads();
#pragma unroll
    for (int p = 0; p < 4; ++p) {
      int idx = t + p * 256;
      int row = idx >> 4, c8 = (idx & 15) * 8;
      *(uint4*)&Klds[row][c8] =
          *(const uint4*)(qkvb + (size_t)(k0 + row) * 1536 + 512 + head * 128 + c8);
    }
#pragma unroll
    for (int p = 0; p < 4; ++p) {
      int idx = t + p * 256;
      int row = idx >> 3, kv8 = (idx & 7) * 8;
      *(uint4*)&Vlds[row][kv8] =
          *(const uint4*)(Vt + (size_t)(head * 128 + row) * NN + k0 + kv8);
    }
    __syncthreads();

    f32x4_t sf[4];
#pragma unroll
    for (int ct = 0; ct < 4; ++ct) sf[ct] = (f32x4_t){0.f, 0.f, 0.f, 0.f};
#pragma unroll
    for (int ks = 0; ks < 4; ++ks) {
#pragma unroll
      for (int ct = 0; ct < 4; ++ct) {
        bf16x8_t kf = *(const bf16x8_t*)&Klds[ct * 16 + lr][ks * 32 + quad * 8];
        sf[ct] = __builtin_amdgcn_mfma_f32_16x16x32_bf16(qf[ks], kf, sf[ct], 0, 0, 0);
      }
    }

    float rs[4] = {0.f, 0.f, 0.f, 0.f};
#pragma unroll
    for (int ct = 0; ct < 4; ++ct) {
#pragma unroll
      for (int r = 0; r < 4; ++r) {
        float e = __expf(sf[ct][r] * ATT_SCALE - ATT_SHIFT);
        Plds[w][quad * 4 + r][ct * 16 + lr] = f2b(e);
        rs[r] += e;
      }
    }
#pragma unroll
    for (int mask = 1; mask < 16; mask <<= 1) {
#pragma unroll
      for (int r = 0; r < 4; ++r) rs[r] += __shfl_xor(rs[r], mask);
    }
#pragma unroll
    for (int r = 0; r < 4; ++r) den[r] += rs[r];

#pragma unroll
    for (int ks2 = 0; ks2 < 2; ++ks2) {
      bf16x8_t pf = *(const bf16x8_t*)&Plds[w][lr][ks2 * 32 + quad * 8];
#pragma unroll
      for (int dt = 0; dt < 8; ++dt) {
        bf16x8_t vf = *(const bf16x8_t*)&Vlds[dt * 16 + lr][ks2 * 32 + quad * 8];
        of[dt] = __builtin_amdgcn_mfma_f32_16x16x32_bf16(pf, vf, of[dt], 0, 0, 0);
      }
    }
  }

  if (lr == 0) {
#pragma unroll
    for (int r = 0; r < 4; ++r)
      dpart[(size_t)(kvs * 4 + head) * NN + q0 + w * 16 + quad * 4 + r] = den[r];
  }
#pragma unroll
  for (int dt = 0; dt < 8; ++dt) {
#pragma unroll
    for (int r = 0; r < 4; ++r) {
      int row = q0 + w * 16 + quad * 4 + r;
      Onum[(size_t)kvs * 2097152 + (size_t)row * 512 + head * 128 + dt * 16 + lr] = of[dt][r];
    }
  }
}

__global__ __launch_bounds__(256) void attn_combine(const float* __restrict__ Onum,
                                                    const float* __restrict__ dpart,
                                                    ushort* __restrict__ aob) {
  int idx = blockIdx.x * 256 + threadIdx.x;
  int row = idx >> 7;
  int c4 = (idx & 127) * 4;
  int head = c4 >> 7;
  float4 a = *(const float4*)(Onum + (size_t)row * 512 + c4);
  float4 b = *(const float4*)(Onum + 2097152 + (size_t)row * 512 + c4);
  float inv = 1.0f / (dpart[(size_t)head * NN + row] + dpart[(size_t)(4 + head) * NN + row]);
  ushort4 o;
  o.x = f2b((a.x + b.x) * inv);
  o.y = f2b((a.y + b.y) * inv);
  o.z = f2b((a.z + b.z) * inv);
  o.w = f2b((a.w + b.w) * inv);
  *(ushort4*)(aob + (size_t)row * 512 + c4) = o;
}

// ---------------- launch ----------------
extern "C" void kernel_launch(void* const* d_in, const int* in_sizes, int n_in,
                              void* d_out, int out_size, void* d_ws, size_t ws_size,
                              hipStream_t stream) {
  const float* x          = (const float*)d_in[0];
  const int*   ei         = (const int*)d_in[1];
  const float* sage_wl    = (const float*)d_in[2];
  const float* sage_wr    = (const float*)d_in[3];
  const float* sage_bl    = (const float*)d_in[4];
  const float* ln_g       = (const float*)d_in[5];
  const float* ln_b       = (const float*)d_in[6];
  const float* conv_w     = (const float*)d_in[7];
  const float* conv_b     = (const float*)d_in[8];
  const float* cnorm_g    = (const float*)d_in[9];
  const float* cnorm_b    = (const float*)d_in[10];
  const float* in_proj_w  = (const float*)d_in[11];
  const float* in_proj_b  = (const float*)d_in[12];
  const float* out_proj_w = (const float*)d_in[13];
  const float* out_proj_b = (const float*)d_in[14];
  const float* anorm_g    = (const float*)d_in[15];
  const float* anorm_b    = (const float*)d_in[16];
  const float* fuse_w     = (const float*)d_in[17];
  const float* fuse_b     = (const float*)d_in[18];
  float* out = (float*)d_out;

  // Workspace lifetime map (~42 MB):
  //  0..1MB   CSR (rowptr 0, cnt 64K, col 128K, invdeg 768K) -> dpart[2][4][NN] after GNN
  //  1..5     h fp32 (GNN)            \
  //  5..7     hb bf16 (until in_proj)  } -> Onum fp32 2x8MB during attention (1..17)
  //  7..9     aggb (GNN)              /
  //  9..13    tmp fp32 (SAGE/conv gemm out)
  // 13..15    c0b bf16 (until in_proj)
  // 15..17    c1b bf16 (conv only)
  // 17..29    qkvb bf16 (until attn)  -> op fp32 17..25, opbf bf16 25..29 after attn
  // 29..33    Vt bf16 (until attn)
  // 33..37    aob bf16 (until out_proj)
  // 37..42    bf16 weights (all-call)
  char* ws = (char*)d_ws;
  const size_t MB = 1 << 20;
  int*    rowptr = (int*)(ws + 0);
  int*    cnt    = (int*)(ws + 65536);
  int*    col    = (int*)(ws + 131072);
  float*  invdeg = (float*)(ws + 786432);
  float*  dpart  = (float*)(ws + 0);
  float*  h    = (float*)(ws + 1 * MB);
  ushort* hb   = (ushort*)(ws + 5 * MB);
  ushort* aggb = (ushort*)(ws + 7 * MB);
  float*  tmp  = (float*)(ws + 9 * MB);
  ushort* c0b  = (ushort*)(ws + 13 * MB);
  ushort* c1b  = (ushort*)(ws + 15 * MB);
  float*  Onum = (float*)(ws + 1 * MB);
  ushort* qkvb = (ushort*)(ws + 17 * MB);
  float*  op   = (float*)(ws + 17 * MB);
  ushort* opbf = (ushort*)(ws + 25 * MB);
  ushort* Vt   = (ushort*)(ws + 29 * MB);
  ushort* aob  = (ushort*)(ws + 33 * MB);
  ushort* wlb  = (ushort*)(ws + 37 * MB);
  ushort* wrb  = (ushort*)(ws + 37 * MB + 786432);
  ushort* cvb  = (ushort*)(ws + 37 * MB + 1572864);
  ushort* ipb  = (ushort*)(ws + 37 * MB + 2752512);
  ushort* wopb = (ushort*)(ws + 37 * MB + 4325376);
  ushort* fwb  = (ushort*)(ws + 37 * MB + 4849664);

  // weight casts
  castw<<<(6 * 256 * 256) / 1024, 256, 0, stream>>>(sage_wl, wlb);
  castw<<<(6 * 256 * 256) / 1024, 256, 0, stream>>>(sage_wr, wrb);
  castconv<<<(3 * 256 * 768) / 256, 256, 0, stream>>>(conv_w, cvb);
  castw<<<(1536 * 512) / 1024, 256, 0, stream>>>(in_proj_w, ipb);
  castw<<<(512 * 512) / 1024, 256, 0, stream>>>(out_proj_w, wopb);
  castw<<<(64 * 512) / 1024, 256, 0, stream>>>(fuse_w, fwb);

  // CSR
  hipMemsetAsync(cnt, 0, NN * sizeof(int), stream);
  hist_kernel<<<EE / 256, 256, 0, stream>>>(ei, cnt);
  scan_kernel<<<1, 1024, 0, stream>>>(cnt, rowptr, invdeg);
  fill_kernel<<<EE / 256, 256, 0, stream>>>(ei, cnt, col);
  hipMemcpyAsync(h, x, (size_t)NN * HH * sizeof(float), hipMemcpyDeviceToDevice, stream);
  castw<<<(NN * HH) / 1024, 256, 0, stream>>>(x, hb);

  // GNN: 6 SAGE layers
  for (int i = 0; i < 6; ++i) {
    agg_kernel<<<NN, 64, 0, stream>>>(hb, rowptr, col, invdeg, aggb);
    gemm_mfma64<<<dim3(64, 4), 256, 0, stream>>>(
        aggb, hb, wlb + (size_t)i * HH * HH, wrb + (size_t)i * HH * HH,
        sage_bl + i * HH, tmp, NN, HH, 512, 256, 256);
    int do_ln = (i < 5) ? 1 : 0;
    const float* gp = do_ln ? (ln_g + i * HH) : ln_g;
    const float* bp = do_ln ? (ln_b + i * HH) : ln_b;
    ln_fuse<<<NN / 4, 256, 0, stream>>>(tmp, gp, bp, h, h, hb, HH, do_ln, 1);
  }

  // CNN: 3 conv layers (bf16 chain)
  const ushort* cin = hb;
  ushort* couts[3] = {c0b, c1b, c0b};
  for (int j = 0; j < 3; ++j) {
    gemm_conv_mfma<<<dim3(64, 4), 256, 0, stream>>>(
        cin, cvb + (size_t)j * HH * 768, conv_b + j * HH, tmp);
    ln_fuse<<<NN / 4, 256, 0, stream>>>(tmp, cnorm_g + j * HH, cnorm_b + j * HH,
                                        nullptr, nullptr, couts[j], HH, 1, 0);
    cin = couts[j];
  }

  // attention
  gemm_mfma<<<dim3(64, 12), 256, 0, stream>>>(
      hb, c0b, ipb, in_proj_b, nullptr, qkvb, NN, 1536, 512, 256);
  vtrans<<<dim3(NN / 32, 512 / 32), 256, 0, stream>>>(qkvb, Vt);
  attn_mfma<<<dim3(NN / 64, 4, 2), 256, 0, stream>>>(qkvb, Vt, Onum, dpart);
  attn_combine<<<(NN * 128) / 256, 256, 0, stream>>>(Onum, dpart, aob);

  gemm_mfma<<<dim3(64, 4), 256, 0, stream>>>(
      aob, nullptr, wopb, out_proj_b, op, nullptr, NN, 512, 512, 512);
  ln_fuse<<<NN / 4, 256, 0, stream>>>(op, anorm_g, anorm_b, nullptr, nullptr, opbf, 512, 1, 0);
  gemm_mfma64<<<dim3(64, 1), 256, 0, stream>>>(
      opbf, nullptr, fwb, nullptr, fuse_b, out, NN, 64, 512, 512, 512);
}